// Round 9
// baseline (209.132 us; speedup 1.0000x reference)
//
#include <hip/hip_runtime.h>

#define NN 100000
#define NE 3200000
#define DD 128
#define NB 391                 // coarse buckets: dst>>8 (256 nodes each)
#define NCH 256                // edge chunks
#define CHUNK (NE / NCH)       // 12500

// ---------------- workspace layout ----------------
// cnt   @ 0        (int NN)      in-degree excl self loop
// start @ 400KB    (int NN)      global CSR offsets
// BT    @ 800KB    (int NB)      bucket totals
// BB    @ 804KB    (int NB)      bucket bases
// Wimg  @ 832KB    (u32 8192)    bf16 W^T, XOR-swizzled LDS image (32KB)
// H     @ 1MB      (int NCH*NB)  per-chunk bucket hist -> within-bucket offsets (400KB)
// esrc  @ 2MB      (int NE)      src ids sorted by dst           [ends 14.8MB]
// P     @ 15MB     (u32 NE)      coarse-partitioned (src<<8)|(dst&255)
// g     @ 15MB     (u32 NN*64)   bf16x2 (cols i,i+64) of (x@W)*dinv — aliases P

typedef __attribute__((ext_vector_type(8))) short bf16x8;
typedef __attribute__((ext_vector_type(4))) float f32x4;

__device__ inline unsigned bf16pair(float a, float b) {
    unsigned ua = __float_as_uint(a); ua = (ua + 0x7fffu + ((ua >> 16) & 1u)) >> 16;
    unsigned ub = __float_as_uint(b); ub = (ub + 0x7fffu + ((ub >> 16) & 1u)) >> 16;
    return ua | (ub << 16);
}
__device__ inline float bflo(unsigned u) { return __uint_as_float(u << 16); }
__device__ inline float bfhi(unsigned u) { return __uint_as_float(u & 0xffff0000u); }

// pass A: per-chunk coarse histogram (LDS) -> H[chunk][bucket].
// First 32 blocks also build the swizzled bf16 W^T image (fused former k_wimg).
__global__ __launch_bounds__(256) void k_hist1(const int* __restrict__ dst, int* __restrict__ H,
                                               const float* __restrict__ W, unsigned* __restrict__ Wimg) {
    if (blockIdx.x < 32) {
        int i = blockIdx.x * 256 + threadIdx.x;   // 8192 = 128 cols x 64 k-pairs
        int c = i >> 6, k2 = i & 63;
        unsigned v = bf16pair(W[(size_t)(k2 * 2) * DD + c], W[(size_t)(k2 * 2 + 1) * DD + c]);
        int byte = c * 256 + ((k2 * 4) ^ ((c & 7) << 4));
        *(unsigned*)((char*)Wimg + byte) = v;
    }
    __shared__ int h[NB];
    for (int i = threadIdx.x; i < NB; i += 256) h[i] = 0;
    __syncthreads();
    const int base = blockIdx.x * CHUNK;
    for (int i = threadIdx.x; i < CHUNK; i += 256)
        atomicAdd(&h[dst[base + i] >> 8], 1);
    __syncthreads();
    for (int i = threadIdx.x; i < NB; i += 256) H[blockIdx.x * NB + i] = h[i];
}

// pass B1: per bucket, scan H column over 256 chunks -> within-bucket chunk offsets + BT
__global__ __launch_bounds__(256) void k_offB1(int* __restrict__ H, int* __restrict__ BT) {
    __shared__ int s[256];
    const int b = blockIdx.x;
    const int t = threadIdx.x;
    int v = H[t * NB + b];
    s[t] = v;
    __syncthreads();
    for (int off = 1; off < 256; off <<= 1) {
        int u = (t >= off) ? s[t - off] : 0;
        __syncthreads();
        s[t] += u;
        __syncthreads();
    }
    H[t * NB + b] = s[t] - v;
    if (t == 255) BT[b] = s[255];
}

// pass B2: exclusive scan of BT -> BB
__global__ __launch_bounds__(512) void k_offB2(const int* __restrict__ BT, int* __restrict__ BB) {
    __shared__ int s[512];
    const int t = threadIdx.x;
    int v = (t < NB) ? BT[t] : 0;
    s[t] = v;
    __syncthreads();
    for (int off = 1; off < 512; off <<= 1) {
        int u = (t >= off) ? s[t - off] : 0;
        __syncthreads();
        s[t] += u;
        __syncthreads();
    }
    if (t < NB) BB[t] = s[t] - v;
}

// pass C: stable coarse partition, LDS cursors, zero global atomics; P packed u32
__global__ __launch_bounds__(256) void k_part(const int* __restrict__ src, const int* __restrict__ dst,
                                              const int* __restrict__ H, const int* __restrict__ BB,
                                              unsigned* __restrict__ P) {
    __shared__ int cur[NB];
    for (int i = threadIdx.x; i < NB; i += 256)
        cur[i] = BB[i] + H[blockIdx.x * NB + i];
    __syncthreads();
    const int base = blockIdx.x * CHUNK;
    for (int i = threadIdx.x; i < CHUNK; i += 256) {
        int s = src[base + i];
        int d = dst[base + i];
        int p = atomicAdd(&cur[d >> 8], 1);   // LDS atomic
        P[p] = ((unsigned)s << 8) | (unsigned)(d & 255);
    }
}

// pass D: per-bucket LDS counting sort; emits esrc + cnt + start
__global__ __launch_bounds__(256) void k_bsort(const unsigned* __restrict__ P, const int* __restrict__ BB,
                                               const int* __restrict__ BT, int* __restrict__ esrc,
                                               int* __restrict__ cnt, int* __restrict__ start) {
    __shared__ int hist[256], red[256], sexcl[256], fil[256];
    const int b = blockIdx.x;
    const int base = BB[b];
    const int n = BT[b];
    const int t = threadIdx.x;
    hist[t] = 0;
    __syncthreads();
    for (int i = t; i < n; i += 256)
        atomicAdd(&hist[P[base + i] & 255u], 1);
    __syncthreads();
    int c = hist[t];
    red[t] = c;
    __syncthreads();
    for (int off = 1; off < 256; off <<= 1) {
        int u = (t >= off) ? red[t - off] : 0;
        __syncthreads();
        red[t] += u;
        __syncthreads();
    }
    int excl = red[t] - c;
    sexcl[t] = excl;
    fil[t] = 0;
    int node = (b << 8) + t;
    if (node < NN) { cnt[node] = c; start[node] = base + excl; }
    __syncthreads();
    for (int i = t; i < n; i += 256) {
        unsigned p = P[base + i];
        int dl = (int)(p & 255u);
        int pos = atomicAdd(&fil[dl], 1);     // LDS atomic
        esrc[base + sexcl[dl] + pos] = (int)(p >> 8);
    }
}

// MFMA GEMM: g = bf16(x) @ bf16(W) * rsqrt(deg), packed (col i, i+64) pairs.
__global__ __launch_bounds__(256) void k_gemm_mfma(
    const float* __restrict__ x, const unsigned* __restrict__ Wimg,
    const int* __restrict__ cnt, unsigned* __restrict__ g) {
    __shared__ unsigned lds[12288];          // Wl 8192 u32 + Xl 4096 u32
    unsigned* Wl = lds;
    unsigned* Xl = lds + 8192;
    const int tid = threadIdx.x;
    {
        const uint4* s4 = (const uint4*)Wimg;
        uint4* d4 = (uint4*)Wl;
        for (int i = tid; i < 2048; i += 256) d4[i] = s4[i];
    }
    const int row0 = blockIdx.x * 64;
    {
        int r = tid >> 2;
        int cchunk = tid & 3;
        int srow = row0 + r; if (srow > NN - 1) srow = NN - 1;
        const float4* xr = (const float4*)(x + (size_t)srow * DD + cchunk * 32);
#pragma unroll
        for (int i = 0; i < 4; ++i) {
            float4 f0 = xr[i * 2], f1 = xr[i * 2 + 1];
            uint4 wv;
            wv.x = bf16pair(f0.x, f0.y); wv.y = bf16pair(f0.z, f0.w);
            wv.z = bf16pair(f1.x, f1.y); wv.w = bf16pair(f1.z, f1.w);
            int byte = r * 256 + (((cchunk * 64) + i * 16) ^ ((r & 7) << 4));
            *(uint4*)((char*)Xl + byte) = wv;
        }
    }
    __syncthreads();
    const int w = tid >> 6;
    const int l = tid & 63;
    const int lr = l & 15, lk = l >> 4;
    bf16x8 a[4];
    {
        int r = w * 16 + lr;
#pragma unroll
        for (int kk = 0; kk < 4; ++kk) {
            int byte = r * 256 + ((kk * 64 + lk * 16) ^ ((r & 7) << 4));
            a[kk] = *(bf16x8*)((char*)Xl + byte);
        }
    }
    f32x4 acc[8];
#pragma unroll
    for (int t = 0; t < 8; ++t) acc[t] = (f32x4){0.f, 0.f, 0.f, 0.f};
#pragma unroll
    for (int t = 0; t < 8; ++t) {
        int c = t * 16 + lr;
#pragma unroll
        for (int kk = 0; kk < 4; ++kk) {
            int byte = c * 256 + ((kk * 64 + lk * 16) ^ ((c & 7) << 4));
            bf16x8 bfr = *(bf16x8*)((char*)Wl + byte);
            acc[t] = __builtin_amdgcn_mfma_f32_16x16x32_bf16(a[kk], bfr, acc[t], 0, 0, 0);
        }
    }
#pragma unroll
    for (int j = 0; j < 4; ++j) {
        int row = row0 + w * 16 + lk * 4 + j;
        if (row < NN) {
            float dinv = rsqrtf((float)(cnt[row] + 1));
#pragma unroll
            for (int t = 0; t < 4; ++t) {
                unsigned v = bf16pair(acc[t][j] * dinv, acc[t + 4][j] * dinv);
                g[(size_t)row * 64 + t * 16 + lr] = v;
            }
        }
    }
}

// one wave per dst node: acc = g[node] + sum_j g[esrc[j]]; out = relu(dinv*acc + b)
// lane i owns cols (i, i+64). 16 unconditional loads in flight.
// esrc reads and out writes are NON-TEMPORAL: keep L2 capacity for hot g rows.
__global__ __launch_bounds__(256) void k_aggregate(
    const unsigned* __restrict__ g, const int* __restrict__ esrc,
    const int* __restrict__ start, const int* __restrict__ cnt,
    const float* __restrict__ b, float* __restrict__ out) {
    int node = blockIdx.x * 4 + (threadIdx.x >> 6);
    if (node >= NN) return;
    int lane = threadIdx.x & 63;
    unsigned u0 = g[(unsigned)node * 64u + lane];
    float ax = bflo(u0), ay = bfhi(u0);
    const int base = start[node];
    const int n = cnt[node];
    const int* ep = esrc + base;
    int j = 0;
    for (; j + 16 <= n; j += 16) {
        int e[16];
#pragma unroll
        for (int u = 0; u < 16; ++u) e[u] = __builtin_nontemporal_load(&ep[j + u]);
        unsigned v[16];
#pragma unroll
        for (int u = 0; u < 16; ++u)
            v[u] = g[(unsigned)e[u] * 64u + lane];
#pragma unroll
        for (int u = 0; u < 16; ++u) { ax += bflo(v[u]); ay += bfhi(v[u]); }
    }
    for (; j + 4 <= n; j += 4) {
        unsigned v0 = g[(unsigned)__builtin_nontemporal_load(&ep[j + 0]) * 64u + lane];
        unsigned v1 = g[(unsigned)__builtin_nontemporal_load(&ep[j + 1]) * 64u + lane];
        unsigned v2 = g[(unsigned)__builtin_nontemporal_load(&ep[j + 2]) * 64u + lane];
        unsigned v3 = g[(unsigned)__builtin_nontemporal_load(&ep[j + 3]) * 64u + lane];
        ax += bflo(v0) + bflo(v1) + bflo(v2) + bflo(v3);
        ay += bfhi(v0) + bfhi(v1) + bfhi(v2) + bfhi(v3);
    }
    for (; j < n; ++j) {
        unsigned v = g[(unsigned)__builtin_nontemporal_load(&ep[j]) * 64u + lane];
        ax += bflo(v); ay += bfhi(v);
    }
    float dinv = rsqrtf((float)(n + 1));
    float bx = b[lane], by = b[lane + 64];
    float ox = fmaxf(fmaf(ax, dinv, bx), 0.f);
    float oy = fmaxf(fmaf(ay, dinv, by), 0.f);
    __builtin_nontemporal_store(ox, &out[(size_t)node * DD + lane]);
    __builtin_nontemporal_store(oy, &out[(size_t)node * DD + lane + 64]);
}

extern "C" void kernel_launch(void* const* d_in, const int* in_sizes, int n_in,
                              void* d_out, int out_size, void* d_ws, size_t ws_size,
                              hipStream_t stream) {
    const float* x = (const float*)d_in[0];
    const int* edge = (const int*)d_in[1];
    const float* W = (const float*)d_in[2];
    const float* b = (const float*)d_in[3];
    float* out = (float*)d_out;

    char* ws = (char*)d_ws;
    int* cnt      = (int*)(ws);
    int* start    = (int*)(ws + 400 * 1024);
    int* BT       = (int*)(ws + 800 * 1024);
    int* BB       = (int*)(ws + 804 * 1024);
    unsigned* Wim = (unsigned*)(ws + 832 * 1024);
    int* H        = (int*)(ws + (1 << 20));
    int* esrc     = (int*)(ws + (2 << 20));
    unsigned* P   = (unsigned*)(ws + (15ull << 20));
    unsigned* g   = (unsigned*)(ws + (15ull << 20));   // aliases P: P dead before gemm

    const int* src = edge;        // edge_index[0]
    const int* dst = edge + NE;   // edge_index[1]

    k_hist1<<<NCH, 256, 0, stream>>>(dst, H, W, Wim);
    k_offB1<<<NB, 256, 0, stream>>>(H, BT);
    k_offB2<<<1, 512, 0, stream>>>(BT, BB);
    k_part<<<NCH, 256, 0, stream>>>(src, dst, H, BB, P);
    k_bsort<<<NB, 256, 0, stream>>>(P, BB, BT, esrc, cnt, start);
    k_gemm_mfma<<<(NN + 63) / 64, 256, 0, stream>>>(x, Wim, cnt, g);
    k_aggregate<<<(NN + 3) / 4, 256, 0, stream>>>(g, esrc, start, cnt, b, out);
}

// Round 10
// 201.181 us; speedup vs baseline: 1.0395x; 1.0395x over previous
//
#include <hip/hip_runtime.h>

#define NN 100000
#define NE 3200000
#define DD 128
#define NB 391                 // coarse buckets: dst>>8 (256 nodes each)
#define NCH 256                // edge chunks
#define CHUNK (NE / NCH)       // 12500
#define PSTAGE 9216            // bsort LDS staging capacity (mean 8192, +4sigma ~8550)

// ---------------- workspace layout ----------------
// cnt   @ 0        (int NN)      in-degree excl self loop
// start @ 400KB    (int NN)      global CSR offsets
// BT    @ 800KB    (int NB)      bucket totals
// BB    @ 804KB    (int NB)      bucket bases
// Wimg  @ 832KB    (u32 8192)    bf16 W^T, XOR-swizzled LDS image (32KB)
// H     @ 1MB      (int NCH*NB)  per-chunk bucket hist -> within-bucket offsets (400KB)
// esrc  @ 2MB      (int NE)      src ids sorted by dst           [ends 14.8MB]
// P     @ 15MB     (u32 NE)      coarse-partitioned (src<<8)|(dst&255)
// g     @ 15MB     (u32 NN*64)   bf16x2 (cols i,i+64) of (x@W)*dinv — aliases P

typedef __attribute__((ext_vector_type(8))) short bf16x8;
typedef __attribute__((ext_vector_type(4))) float f32x4;

__device__ inline unsigned bf16pair(float a, float b) {
    unsigned ua = __float_as_uint(a); ua = (ua + 0x7fffu + ((ua >> 16) & 1u)) >> 16;
    unsigned ub = __float_as_uint(b); ub = (ub + 0x7fffu + ((ub >> 16) & 1u)) >> 16;
    return ua | (ub << 16);
}
__device__ inline float bflo(unsigned u) { return __uint_as_float(u << 16); }
__device__ inline float bfhi(unsigned u) { return __uint_as_float(u & 0xffff0000u); }

// pass A: per-chunk coarse histogram (LDS) -> H[chunk][bucket].
// First 32 blocks also build the swizzled bf16 W^T image (fused former k_wimg).
__global__ __launch_bounds__(256) void k_hist1(const int* __restrict__ dst, int* __restrict__ H,
                                               const float* __restrict__ W, unsigned* __restrict__ Wimg) {
    if (blockIdx.x < 32) {
        int i = blockIdx.x * 256 + threadIdx.x;   // 8192 = 128 cols x 64 k-pairs
        int c = i >> 6, k2 = i & 63;
        unsigned v = bf16pair(W[(size_t)(k2 * 2) * DD + c], W[(size_t)(k2 * 2 + 1) * DD + c]);
        int byte = c * 256 + ((k2 * 4) ^ ((c & 7) << 4));
        *(unsigned*)((char*)Wimg + byte) = v;
    }
    __shared__ int h[NB];
    for (int i = threadIdx.x; i < NB; i += 256) h[i] = 0;
    __syncthreads();
    const int base = blockIdx.x * CHUNK;
    for (int i = threadIdx.x; i < CHUNK; i += 256)
        atomicAdd(&h[dst[base + i] >> 8], 1);
    __syncthreads();
    for (int i = threadIdx.x; i < NB; i += 256) H[blockIdx.x * NB + i] = h[i];
}

// pass B1: per bucket, scan H column over 256 chunks -> within-bucket chunk offsets + BT
__global__ __launch_bounds__(256) void k_offB1(int* __restrict__ H, int* __restrict__ BT) {
    __shared__ int s[256];
    const int b = blockIdx.x;
    const int t = threadIdx.x;
    int v = H[t * NB + b];
    s[t] = v;
    __syncthreads();
    for (int off = 1; off < 256; off <<= 1) {
        int u = (t >= off) ? s[t - off] : 0;
        __syncthreads();
        s[t] += u;
        __syncthreads();
    }
    H[t * NB + b] = s[t] - v;
    if (t == 255) BT[b] = s[255];
}

// pass B2: exclusive scan of BT -> BB
__global__ __launch_bounds__(512) void k_offB2(const int* __restrict__ BT, int* __restrict__ BB) {
    __shared__ int s[512];
    const int t = threadIdx.x;
    int v = (t < NB) ? BT[t] : 0;
    s[t] = v;
    __syncthreads();
    for (int off = 1; off < 512; off <<= 1) {
        int u = (t >= off) ? s[t - off] : 0;
        __syncthreads();
        s[t] += u;
        __syncthreads();
    }
    if (t < NB) BB[t] = s[t] - v;
}

// pass C: stable coarse partition, LDS cursors, zero global atomics; P packed u32
__global__ __launch_bounds__(256) void k_part(const int* __restrict__ src, const int* __restrict__ dst,
                                              const int* __restrict__ H, const int* __restrict__ BB,
                                              unsigned* __restrict__ P) {
    __shared__ int cur[NB];
    for (int i = threadIdx.x; i < NB; i += 256)
        cur[i] = BB[i] + H[blockIdx.x * NB + i];
    __syncthreads();
    const int base = blockIdx.x * CHUNK;
    for (int i = threadIdx.x; i < CHUNK; i += 256) {
        int s = src[base + i];
        int d = dst[base + i];
        int p = atomicAdd(&cur[d >> 8], 1);   // LDS atomic
        P[p] = ((unsigned)s << 8) | (unsigned)(d & 255);
    }
}

// pass D: per-bucket LDS counting sort; stages the bucket's P segment in LDS
// (single global pass over P). Emits esrc + cnt + start.
__global__ __launch_bounds__(256) void k_bsort(const unsigned* __restrict__ P, const int* __restrict__ BB,
                                               const int* __restrict__ BT, int* __restrict__ esrc,
                                               int* __restrict__ cnt, int* __restrict__ start) {
    __shared__ int hist[256], red[256], sexcl[256], fil[256];
    __shared__ unsigned Ps[PSTAGE];
    const int b = blockIdx.x;
    const int base = BB[b];
    const int n = BT[b];
    const int t = threadIdx.x;
    const bool fits = (n <= PSTAGE);          // block-uniform
    hist[t] = 0;
    __syncthreads();
    for (int i = t; i < n; i += 256) {
        unsigned p = P[base + i];
        if (fits) Ps[i] = p;
        atomicAdd(&hist[p & 255u], 1);
    }
    __syncthreads();
    int c = hist[t];
    red[t] = c;
    __syncthreads();
    for (int off = 1; off < 256; off <<= 1) {
        int u = (t >= off) ? red[t - off] : 0;
        __syncthreads();
        red[t] += u;
        __syncthreads();
    }
    int excl = red[t] - c;
    sexcl[t] = excl;
    fil[t] = 0;
    int node = (b << 8) + t;
    if (node < NN) { cnt[node] = c; start[node] = base + excl; }
    __syncthreads();
    for (int i = t; i < n; i += 256) {
        unsigned p = fits ? Ps[i] : P[base + i];
        int dl = (int)(p & 255u);
        int pos = atomicAdd(&fil[dl], 1);     // LDS atomic
        esrc[base + sexcl[dl] + pos] = (int)(p >> 8);
    }
}

// MFMA GEMM: g = bf16(x) @ bf16(W) * rsqrt(deg), packed (col i, i+64) pairs.
// 128 rows/block, 4 waves; A-fragments loaded DIRECT from global x (fp32->bf16
// in-register, per-wave pattern = 16 rows x 128B contiguous -> coalesced).
// Only W lives in LDS (32KB, from pre-swizzled image).
__global__ __launch_bounds__(256) void k_gemm_mfma(
    const float* __restrict__ x, const unsigned* __restrict__ Wimg,
    const int* __restrict__ cnt, unsigned* __restrict__ g) {
    __shared__ unsigned Wl[8192];            // 32 KB
    const int tid = threadIdx.x;
    {
        const uint4* s4 = (const uint4*)Wimg;
        uint4* d4 = (uint4*)Wl;
        for (int i = tid; i < 2048; i += 256) d4[i] = s4[i];
    }
    const int row0 = blockIdx.x * 128;
    const int w = tid >> 6;
    const int l = tid & 63;
    const int lr = l & 15, lk = l >> 4;
    bf16x8 a[2][4];
#pragma unroll
    for (int rg = 0; rg < 2; ++rg) {
        int r = row0 + w * 32 + rg * 16 + lr;
        if (r > NN - 1) r = NN - 1;
        const float* xr = x + (size_t)r * DD;
#pragma unroll
        for (int kk = 0; kk < 4; ++kk) {
            float4 f0 = *(const float4*)(xr + kk * 32 + lk * 8);
            float4 f1 = *(const float4*)(xr + kk * 32 + lk * 8 + 4);
            uint4 wv;
            wv.x = bf16pair(f0.x, f0.y); wv.y = bf16pair(f0.z, f0.w);
            wv.z = bf16pair(f1.x, f1.y); wv.w = bf16pair(f1.z, f1.w);
            a[rg][kk] = *(bf16x8*)&wv;
        }
    }
    __syncthreads();
    f32x4 acc[2][8];
#pragma unroll
    for (int rg = 0; rg < 2; ++rg)
#pragma unroll
        for (int t = 0; t < 8; ++t) acc[rg][t] = (f32x4){0.f, 0.f, 0.f, 0.f};
#pragma unroll
    for (int t = 0; t < 8; ++t) {
        int c = t * 16 + lr;
#pragma unroll
        for (int kk = 0; kk < 4; ++kk) {
            int byte = c * 256 + ((kk * 64 + lk * 16) ^ ((c & 7) << 4));
            bf16x8 bfr = *(bf16x8*)((char*)Wl + byte);
            acc[0][t] = __builtin_amdgcn_mfma_f32_16x16x32_bf16(a[0][kk], bfr, acc[0][t], 0, 0, 0);
            acc[1][t] = __builtin_amdgcn_mfma_f32_16x16x32_bf16(a[1][kk], bfr, acc[1][t], 0, 0, 0);
        }
    }
#pragma unroll
    for (int rg = 0; rg < 2; ++rg)
#pragma unroll
    for (int j = 0; j < 4; ++j) {
        int row = row0 + w * 32 + rg * 16 + lk * 4 + j;
        if (row < NN) {
            float dinv = rsqrtf((float)(cnt[row] + 1));
#pragma unroll
            for (int t = 0; t < 4; ++t) {
                unsigned v = bf16pair(acc[rg][t][j] * dinv, acc[rg][t + 4][j] * dinv);
                g[(size_t)row * 64 + t * 16 + lr] = v;
            }
        }
    }
}

// one wave per dst node: acc = g[node] + sum_j g[esrc[j]]; out = relu(dinv*acc + b)
// lane i owns cols (i, i+64). 16 unconditional loads in flight; plain (scalar-path)
// esrc loads; non-temporal stores for out (write-once, keep L2 for g).
__global__ __launch_bounds__(256) void k_aggregate(
    const unsigned* __restrict__ g, const int* __restrict__ esrc,
    const int* __restrict__ start, const int* __restrict__ cnt,
    const float* __restrict__ b, float* __restrict__ out) {
    int node = blockIdx.x * 4 + (threadIdx.x >> 6);
    if (node >= NN) return;
    int lane = threadIdx.x & 63;
    unsigned u0 = g[(unsigned)node * 64u + lane];
    float ax = bflo(u0), ay = bfhi(u0);
    const int base = start[node];
    const int n = cnt[node];
    const int* ep = esrc + base;
    int j = 0;
    for (; j + 16 <= n; j += 16) {
        unsigned v[16];
#pragma unroll
        for (int u = 0; u < 16; ++u)
            v[u] = g[(unsigned)ep[j + u] * 64u + lane];
#pragma unroll
        for (int u = 0; u < 16; ++u) { ax += bflo(v[u]); ay += bfhi(v[u]); }
    }
    for (; j + 4 <= n; j += 4) {
        unsigned v0 = g[(unsigned)ep[j + 0] * 64u + lane];
        unsigned v1 = g[(unsigned)ep[j + 1] * 64u + lane];
        unsigned v2 = g[(unsigned)ep[j + 2] * 64u + lane];
        unsigned v3 = g[(unsigned)ep[j + 3] * 64u + lane];
        ax += bflo(v0) + bflo(v1) + bflo(v2) + bflo(v3);
        ay += bfhi(v0) + bfhi(v1) + bfhi(v2) + bfhi(v3);
    }
    for (; j < n; ++j) {
        unsigned v = g[(unsigned)ep[j] * 64u + lane];
        ax += bflo(v); ay += bfhi(v);
    }
    float dinv = rsqrtf((float)(n + 1));
    float bx = b[lane], by = b[lane + 64];
    float ox = fmaxf(fmaf(ax, dinv, bx), 0.f);
    float oy = fmaxf(fmaf(ay, dinv, by), 0.f);
    __builtin_nontemporal_store(ox, &out[(size_t)node * DD + lane]);
    __builtin_nontemporal_store(oy, &out[(size_t)node * DD + lane + 64]);
}

extern "C" void kernel_launch(void* const* d_in, const int* in_sizes, int n_in,
                              void* d_out, int out_size, void* d_ws, size_t ws_size,
                              hipStream_t stream) {
    const float* x = (const float*)d_in[0];
    const int* edge = (const int*)d_in[1];
    const float* W = (const float*)d_in[2];
    const float* b = (const float*)d_in[3];
    float* out = (float*)d_out;

    char* ws = (char*)d_ws;
    int* cnt      = (int*)(ws);
    int* start    = (int*)(ws + 400 * 1024);
    int* BT       = (int*)(ws + 800 * 1024);
    int* BB       = (int*)(ws + 804 * 1024);
    unsigned* Wim = (unsigned*)(ws + 832 * 1024);
    int* H        = (int*)(ws + (1 << 20));
    int* esrc     = (int*)(ws + (2 << 20));
    unsigned* P   = (unsigned*)(ws + (15ull << 20));
    unsigned* g   = (unsigned*)(ws + (15ull << 20));   // aliases P: P dead before gemm

    const int* src = edge;        // edge_index[0]
    const int* dst = edge + NE;   // edge_index[1]

    k_hist1<<<NCH, 256, 0, stream>>>(dst, H, W, Wim);
    k_offB1<<<NB, 256, 0, stream>>>(H, BT);
    k_offB2<<<1, 512, 0, stream>>>(BT, BB);
    k_part<<<NCH, 256, 0, stream>>>(src, dst, H, BB, P);
    k_bsort<<<NB, 256, 0, stream>>>(P, BB, BT, esrc, cnt, start);
    k_gemm_mfma<<<(NN + 127) / 128, 256, 0, stream>>>(x, Wim, cnt, g);
    k_aggregate<<<(NN + 3) / 4, 256, 0, stream>>>(g, esrc, start, cnt, b, out);
}